// Round 12
// baseline (456.301 us; speedup 1.0000x reference)
//
#include <hip/hip_runtime.h>
#include <cmath>

#define NN 50000
#define EE 800000
#define ETOT (EE + NN)
#define NSCAN ((NN + 1023) / 1024)
#define SROWS 50048   // padded rows for head-major logit arrays

typedef __bf16 v8bf __attribute__((ext_vector_type(8)));
typedef float f32x4 __attribute__((ext_vector_type(4)));
typedef float f32x2 __attribute__((ext_vector_type(2)));

__device__ __forceinline__ float lrelu(float x){ return x > 0.0f ? x : 0.2f * x; }
__device__ __forceinline__ unsigned short f2bf_rne(float x){
  unsigned int u = __float_as_uint(x);
  u += 0x7fffu + ((u >> 16) & 1u);
  return (unsigned short)(u >> 16);
}
__device__ __forceinline__ float bf2f(unsigned short b){
  return __uint_as_float(((unsigned int)b) << 16);
}
// packed accumulate: acc[4] of float2 -> v_pk_fma_f32
__device__ __forceinline__ void fma8p(f32x2* acc, float w, uint4 u){
  f32x2 w2 = {w, w};
  f32x2 a0, a1, a2, a3;
  a0[0] = __uint_as_float(u.x << 16); a0[1] = __uint_as_float(u.x & 0xffff0000u);
  a1[0] = __uint_as_float(u.y << 16); a1[1] = __uint_as_float(u.y & 0xffff0000u);
  a2[0] = __uint_as_float(u.z << 16); a2[1] = __uint_as_float(u.z & 0xffff0000u);
  a3[0] = __uint_as_float(u.w << 16); a3[1] = __uint_as_float(u.w & 0xffff0000u);
  acc[0] += w2 * a0;
  acc[1] += w2 * a1;
  acc[2] += w2 * a2;
  acc[3] += w2 * a3;
}

// ---------------- CSR build ----------------
__global__ void k_hist(const int* __restrict__ dst, int* __restrict__ cnt){
  int i = blockIdx.x * 256 + threadIdx.x;
  if (i >= ETOT) return;
  int d = (i < EE) ? dst[i] : (i - EE);
  atomicAdd(&cnt[d], 1);
}

__global__ void k_scan1(const int* __restrict__ cnt, int* __restrict__ part){
  __shared__ int sm[256];
  int b = blockIdx.x, t = threadIdx.x;
  int base = b * 1024 + t * 4;
  int s = 0;
  #pragma unroll
  for (int j = 0; j < 4; j++) if (base + j < NN) s += cnt[base + j];
  sm[t] = s; __syncthreads();
  for (int off = 128; off; off >>= 1){
    if (t < off) sm[t] += sm[t + off];
    __syncthreads();
  }
  if (t == 0) part[b] = sm[0];
}

__global__ void k_scan2(const int* __restrict__ part, int* __restrict__ part2){
  if (threadIdx.x == 0 && blockIdx.x == 0){
    int run = 0;
    for (int i = 0; i < NSCAN; i++){ part2[i] = run; run += part[i]; }
  }
}

__global__ void k_scan3(const int* __restrict__ cnt, const int* __restrict__ part2,
                        int* __restrict__ rowptr){
  __shared__ int sm[256];
  int b = blockIdx.x, t = threadIdx.x;
  int base = b * 1024 + t * 4;
  int v[4]; int s = 0;
  #pragma unroll
  for (int j = 0; j < 4; j++){ v[j] = (base + j < NN) ? cnt[base + j] : 0; s += v[j]; }
  sm[t] = s; __syncthreads();
  for (int off = 1; off < 256; off <<= 1){
    int x = (t >= off) ? sm[t - off] : 0;
    __syncthreads();
    sm[t] += x;
    __syncthreads();
  }
  int run = part2[b] + sm[t] - s;
  #pragma unroll
  for (int j = 0; j < 4; j++){
    if (base + j < NN){ rowptr[base + j] = run; run += v[j]; }
  }
  if (b == 0 && t == 0) rowptr[NN] = ETOT;
}

__global__ void k_scatter(const int* __restrict__ src, const int* __restrict__ dst,
                          const int* __restrict__ rowptr, int* __restrict__ fill,
                          int* __restrict__ csr){
  int i = blockIdx.x * 256 + threadIdx.x;
  if (i >= ETOT) return;
  int s, d;
  if (i < EE){ s = src[i]; d = dst[i]; } else { s = d = i - EE; }
  int pos = rowptr[d] + atomicAdd(&fill[d], 1);
  csr[pos] = s;
}

// ---------------- weight conversion: fp32 [.,K,N] -> bf16 hi/lo tiled -------
// Output tile layout [K/8][NX][8] with NX >= N (extra cols pre-zeroed).
__global__ void k_convB(const float* __restrict__ B, unsigned short* __restrict__ bh,
                        unsigned short* __restrict__ bl, int K, int N, int NX, int total){
  int i = blockIdx.x * 256 + threadIdx.x;
  if (i >= total) return;
  int per = K * N;
  int h = i / per, rem = i - h * per;
  int k = rem / N, n = rem - k * N;
  float x = B[i];
  unsigned short hb = f2bf_rne(x);
  unsigned short lb = f2bf_rne(x - bf2f(hb));
  size_t o = (size_t)h * (K >> 3) * NX * 8 + ((size_t)(k >> 3) * NX + n) * 8 + (k & 7);
  bh[o] = hb; bl[o] = lb;
}

// ---------------- fold attention vectors into B: cols N, N+1 = W@att_s, W@att_d
__global__ void k_convAtt(const float* __restrict__ W, const float* __restrict__ att_s,
                          const float* __restrict__ att_d,
                          unsigned short* __restrict__ bh, unsigned short* __restrict__ bl,
                          int K, int N, int NX){
  int h = blockIdx.x, k = threadIdx.x;
  const float* wrow = W + ((size_t)h * K + k) * N;
  const float* as = att_s + (size_t)h * N;
  const float* ad = att_d + (size_t)h * N;
  float s = 0.f, d = 0.f;
  for (int n = 0; n < N; n++){ float w = wrow[n]; s += w * as[n]; d += w * ad[n]; }
  size_t base = (size_t)h * (K >> 3) * NX * 8 + (size_t)(k >> 3) * NX * 8 + (k & 7);
  unsigned short hs = f2bf_rne(s);
  bh[base + (size_t)N * 8] = hs;
  bl[base + (size_t)N * 8] = f2bf_rne(s - bf2f(hs));
  unsigned short hd = f2bf_rne(d);
  bh[base + (size_t)(N + 1) * 8] = hd;
  bl[base + (size_t)(N + 1) * 8] = f2bf_rne(d - bf2f(hd));
}

// ---------------- layer-1 GEMM: A single bf16 (staged from fp32), B split ----
// Attention row-dots computed as 2 extra B columns (tile ct = BN/16): no
// epilogue shuffles. 2 MFMA per (rt,ct) instead of 3.
template<int BN, int BNX, int OSTR>
__global__ __launch_bounds__(256) void gemm_split(const float* __restrict__ A,
                                                  const unsigned short* __restrict__ Bh,
                                                  const unsigned short* __restrict__ Bl,
                                                  unsigned short* __restrict__ out,
                                                  int M, int K,
                                                  float* __restrict__ ssrc,
                                                  float* __restrict__ sdst){
  const int t = threadIdx.x;
  const int wv = t >> 6, lane = t & 63;
  const int m0 = blockIdx.x * 128;
  const int h = blockIdx.y;
  A  += (size_t)h * M * K;
  Bh += (size_t)h * (K >> 3) * BNX * 8;
  Bl += (size_t)h * (K >> 3) * BNX * 8;
  const int colOff = h * BN;

  __shared__ v8bf sA[4][128];
  __shared__ v8bf sBh[4][BNX];
  __shared__ v8bf sBl[4][BNX];

  f32x4 acc[2][BNX / 16];
  #pragma unroll
  for (int i = 0; i < 2; i++)
    #pragma unroll
    for (int j = 0; j < BNX / 16; j++){
      f32x4 z = {0.f, 0.f, 0.f, 0.f};
      acc[i][j] = z;
    }

  const int mRow = t & 127;
  const int kh = (t >> 7) * 16;
  const bool valid = (m0 + mRow) < M;
  const int q = lane >> 4, lm = lane & 15;

  for (int k0 = 0; k0 < K; k0 += 32){
    const float* ap = A + (size_t)(m0 + mRow) * K + k0 + kh;
    float4 v0, v1, v2, v3;
    if (valid){
      v0 = *(const float4*)(ap);
      v1 = *(const float4*)(ap + 4);
      v2 = *(const float4*)(ap + 8);
      v3 = *(const float4*)(ap + 12);
    } else {
      v0 = v1 = v2 = v3 = make_float4(0.f, 0.f, 0.f, 0.f);
    }
    #pragma unroll
    for (int g = 0; g < 2; g++){
      float xv[8];
      if (g == 0){ xv[0]=v0.x; xv[1]=v0.y; xv[2]=v0.z; xv[3]=v0.w; xv[4]=v1.x; xv[5]=v1.y; xv[6]=v1.z; xv[7]=v1.w; }
      else       { xv[0]=v2.x; xv[1]=v2.y; xv[2]=v2.z; xv[3]=v2.w; xv[4]=v3.x; xv[5]=v3.y; xv[6]=v3.z; xv[7]=v3.w; }
      v8bf H;
      #pragma unroll
      for (int i = 0; i < 8; i++) H[i] = (__bf16)xv[i];   // v_cvt_pk_bf16_f32
      sA[(kh >> 3) + g][mRow] = H;
    }
    {
      const v8bf* gh = (const v8bf*)Bh + (size_t)(k0 >> 3) * BNX;
      const v8bf* gl = (const v8bf*)Bl + (size_t)(k0 >> 3) * BNX;
      v8bf* dh = &sBh[0][0];
      v8bf* dl = &sBl[0][0];
      #pragma unroll
      for (int i = t; i < 4 * BNX; i += 256){ dh[i] = gh[i]; dl[i] = gl[i]; }
    }
    __syncthreads();
    v8bf ah[2];
    #pragma unroll
    for (int rt = 0; rt < 2; rt++)
      ah[rt] = sA[q][wv * 32 + rt * 16 + lm];
    #pragma unroll
    for (int ct = 0; ct < BNX / 16; ct++){
      v8bf bh = sBh[q][ct * 16 + lm];
      v8bf bl = sBl[q][ct * 16 + lm];
      #pragma unroll
      for (int rt = 0; rt < 2; rt++){
        acc[rt][ct] = __builtin_amdgcn_mfma_f32_16x16x32_bf16(ah[rt], bh, acc[rt][ct], 0, 0, 0);
        acc[rt][ct] = __builtin_amdgcn_mfma_f32_16x16x32_bf16(ah[rt], bl, acc[rt][ct], 0, 0, 0);
      }
    }
    __syncthreads();
  }

  // ---- epilogue: C-store + att logits from the extra tile (no shuffles) ----
  #pragma unroll
  for (int rt = 0; rt < 2; rt++){
    #pragma unroll
    for (int reg = 0; reg < 4; reg++){
      int r = m0 + wv * 32 + rt * 16 + q * 4 + reg;
      if (r < M){
        unsigned short* orow = out + (size_t)r * OSTR + colOff + lm;
        #pragma unroll
        for (int ct = 0; ct < BN / 16; ct++)
          orow[ct * 16] = f2bf_rne(acc[rt][ct][reg]);
        float v = acc[rt][BN / 16][reg];
        if (lm == 0) ssrc[(size_t)h * SROWS + r] = v;
        else if (lm == 1) sdst[(size_t)h * SROWS + r] = v;
      }
    }
  }
}

// ---------------- layer-2 GEMM (A single bf16, B split hi/lo) ---------------
template<int BN, int OSTR>
__global__ __launch_bounds__(256) void gemm_ps(const unsigned short* __restrict__ Ah,
                                               const unsigned short* __restrict__ Bh,
                                               const unsigned short* __restrict__ Bl,
                                               unsigned short* __restrict__ out,
                                               int M, int K,
                                               const float* __restrict__ att_s,
                                               const float* __restrict__ att_d,
                                               float* __restrict__ ssrc,
                                               float* __restrict__ sdst){
  const int t = threadIdx.x;
  const int wv = t >> 6, lane = t & 63;
  const int m0 = blockIdx.x * 128;
  const int h = blockIdx.y;
  const int colOff = h * BN;

  __shared__ v8bf sAh[4][128];
  __shared__ v8bf sBh[4][BN];
  __shared__ v8bf sBl[4][BN];

  f32x4 acc[2][BN / 16];
  #pragma unroll
  for (int i = 0; i < 2; i++)
    #pragma unroll
    for (int j = 0; j < BN / 16; j++){
      f32x4 z = {0.f, 0.f, 0.f, 0.f};
      acc[i][j] = z;
    }

  const int mRow = t & 127;
  const int kh = (t >> 7) * 16;
  const bool valid = (m0 + mRow) < M;
  const int q = lane >> 4, lm = lane & 15;

  for (int k0 = 0; k0 < K; k0 += 32){
    // ---- stage A: pure 16B copies ----
    const unsigned short* aph = Ah + (size_t)(m0 + mRow) * K + k0 + kh;
    uint4 h0, h1;
    if (valid){
      h0 = *(const uint4*)(aph);
      h1 = *(const uint4*)(aph + 8);
    } else {
      h0 = h1 = make_uint4(0, 0, 0, 0);
    }
    int k8 = kh >> 3;
    sAh[k8][mRow]     = *(v8bf*)&h0;
    sAh[k8 + 1][mRow] = *(v8bf*)&h1;
    {
      const v8bf* gh = (const v8bf*)Bh + (size_t)(k0 >> 3) * BN;
      const v8bf* gl = (const v8bf*)Bl + (size_t)(k0 >> 3) * BN;
      v8bf* dh = &sBh[0][0];
      v8bf* dl = &sBl[0][0];
      #pragma unroll
      for (int i = t; i < 4 * BN; i += 256){ dh[i] = gh[i]; dl[i] = gl[i]; }
    }
    __syncthreads();
    v8bf ah[2];
    #pragma unroll
    for (int rt = 0; rt < 2; rt++){
      int m = wv * 32 + rt * 16 + lm;
      ah[rt] = sAh[q][m];
    }
    #pragma unroll
    for (int ct = 0; ct < BN / 16; ct++){
      v8bf bh = sBh[q][ct * 16 + lm];
      v8bf bl = sBl[q][ct * 16 + lm];
      #pragma unroll
      for (int rt = 0; rt < 2; rt++){
        acc[rt][ct] = __builtin_amdgcn_mfma_f32_16x16x32_bf16(ah[rt], bh, acc[rt][ct], 0, 0, 0);
        acc[rt][ct] = __builtin_amdgcn_mfma_f32_16x16x32_bf16(ah[rt], bl, acc[rt][ct], 0, 0, 0);
      }
    }
    __syncthreads();
  }

  float asv[BN / 16], adv[BN / 16];
  #pragma unroll
  for (int ct = 0; ct < BN / 16; ct++){
    asv[ct] = att_s[h * BN + ct * 16 + lm];
    adv[ct] = att_d[h * BN + ct * 16 + lm];
  }

  #pragma unroll
  for (int rt = 0; rt < 2; rt++){
    #pragma unroll
    for (int reg = 0; reg < 4; reg++){
      int r = m0 + wv * 32 + rt * 16 + q * 4 + reg;
      float d0 = 0.f, d1 = 0.f;
      #pragma unroll
      for (int ct = 0; ct < BN / 16; ct++){
        float v = acc[rt][ct][reg];
        d0 += v * asv[ct];
        d1 += v * adv[ct];
      }
      #pragma unroll
      for (int off = 1; off < 16; off <<= 1){
        d0 += __shfl_xor(d0, off, 64);
        d1 += __shfl_xor(d1, off, 64);
      }
      if (r < M){
        unsigned short* orow = out + (size_t)r * OSTR + colOff + lm;
        #pragma unroll
        for (int ct = 0; ct < BN / 16; ct++)
          orow[ct * 16] = f2bf_rne(acc[rt][ct][reg]);
        if (lm == 0){
          ssrc[(size_t)h * SROWS + r] = d0;
          sdst[(size_t)h * SROWS + r] = d1;
        }
      }
    }
  }
}

// ---------------- layer-1 aggregation: 16-lane group per (node, head) --------
// Round-4/9 structure (proven locality optimum): per-head grid.y (12.8MB hot
// slice), 4 nodes/wave, no shuffles (same-address broadcast of csr/ssrc),
// depth-2 pipeline, packed v_pk_fma_f32. x1 written as SINGLE bf16 (hi only).
__global__ __launch_bounds__(256) void k_agg1(const int* __restrict__ rowptr,
                                              const int* __restrict__ csr,
                                              const float* __restrict__ ssrc,
                                              const float* __restrict__ sdst,
                                              const unsigned short* __restrict__ xs_all,
                                              const float* __restrict__ bias,
                                              unsigned short* __restrict__ x1h){
  int tid = blockIdx.x * 256 + threadIdx.x;
  int n = tid >> 4;
  int lm = threadIdx.x & 15;
  int h = blockIdx.y;
  if (n >= NN) return;
  int start = rowptr[n], end = rowptr[n + 1];
  const float* sp = ssrc + (size_t)h * SROWS;
  float sdn = sdst[(size_t)h * SROWS + n];
  const uint4* xp = (const uint4*)xs_all + h * 16 + lm;

  float sloc = 0.f;
  f32x2 acc[4];
  #pragma unroll
  for (int i = 0; i < 4; i++){ f32x2 z = {0.f, 0.f}; acc[i] = z; }

  // depth-2 pipeline: consume edge e while loading e+1
  int e = start;
  int sA = csr[e];
  float svA = sp[sA];
  uint4 uA = xp[(size_t)sA * 64];
  for (; e + 1 < end; e++){
    int sB = csr[e + 1];
    float svB = sp[sB];
    uint4 uB = xp[(size_t)sB * 64];
    float w = __expf(lrelu(svA + sdn));
    sloc += w;
    fma8p(acc, w, uA);
    svA = svB; uA = uB;
  }
  float w = __expf(lrelu(svA + sdn));
  sloc += w;
  fma8p(acc, w, uA);

  float inv = 1.f / sloc;

  const float* bp = bias + h * 128 + lm * 8;
  float4 b0 = *(const float4*)bp, b1 = *(const float4*)(bp + 4);
  float bb[8] = {b0.x, b0.y, b0.z, b0.w, b1.x, b1.y, b1.z, b1.w};
  union { uint4 q; unsigned short u[8]; } HH;
  #pragma unroll
  for (int i = 0; i < 8; i++){
    float o = lrelu(acc[i >> 1][i & 1] * inv + bb[i]);
    HH.u[i] = f2bf_rne(o);
  }
  size_t ofs = (size_t)n * 512 + h * 128 + lm * 8;
  *(uint4*)(x1h + ofs) = HH.q;
}

// ---------------- layer-2 aggregation: 8-lane group per node ------------------
// Round-4/9 structure + packed fma. sloc is full denominator per-lane.
__global__ __launch_bounds__(256) void k_agg2(const int* __restrict__ rowptr,
                                              const int* __restrict__ csr,
                                              const float* __restrict__ ssrc,
                                              const float* __restrict__ sdst,
                                              const unsigned short* __restrict__ xs2,
                                              const float* __restrict__ bias,
                                              float* __restrict__ outp){
  int tid = blockIdx.x * 256 + threadIdx.x;
  int n = tid >> 3;
  int lm = threadIdx.x & 7;
  if (n >= NN) return;
  int start = rowptr[n], end = rowptr[n + 1];
  float sdn = sdst[n];
  const uint4* xp = (const uint4*)xs2 + lm;

  float sloc = 0.f;
  f32x2 acc[4];
  #pragma unroll
  for (int i = 0; i < 4; i++){ f32x2 z = {0.f, 0.f}; acc[i] = z; }

  int e = start;
  int sA = csr[e];
  float svA = ssrc[sA];
  uint4 uA = xp[(size_t)sA * 8];
  for (; e + 1 < end; e++){
    int sB = csr[e + 1];
    float svB = ssrc[sB];
    uint4 uB = xp[(size_t)sB * 8];
    float w = __expf(lrelu(svA + sdn));
    sloc += w;
    fma8p(acc, w, uA);
    svA = svB; uA = uB;
  }
  float w = __expf(lrelu(svA + sdn));
  sloc += w;
  fma8p(acc, w, uA);

  float inv = 1.f / sloc;

  float o[8];
  #pragma unroll
  for (int i = 0; i < 8; i++)
    o[i] = tanhf(lrelu(acc[i >> 1][i & 1] * inv + bias[lm * 8 + i]));
  float* op = outp + (size_t)n * 64 + lm * 8;
  *(float4*)op       = make_float4(o[0], o[1], o[2], o[3]);
  *(float4*)(op + 4) = make_float4(o[4], o[5], o[6], o[7]);
}

extern "C" void kernel_launch(void* const* d_in, const int* in_sizes, int n_in,
                              void* d_out, int out_size, void* d_ws, size_t ws_size,
                              hipStream_t stream){
  const float* type_emb  = (const float*)d_in[0];
  const int*   edge      = (const int*)d_in[1];
  const float* W         = (const float*)d_in[2];
  const float* att_src   = (const float*)d_in[3];
  const float* att_dst   = (const float*)d_in[4];
  const float* bias      = (const float*)d_in[5];
  const float* W_out     = (const float*)d_in[6];
  const float* att_src_o = (const float*)d_in[7];
  const float* att_dst_o = (const float*)d_in[8];
  const float* bias_o    = (const float*)d_in[9];
  float* out = (float*)d_out;
  (void)in_sizes; (void)n_in; (void)out_size; (void)ws_size;

  char* ws = (char*)d_ws;
  size_t off = 0;
  auto alloc = [&](size_t bytes) -> void* {
    void* p = ws + off;
    off = (off + bytes + 255) & ~(size_t)255;
    return p;
  };
  unsigned short* xs_all = (unsigned short*)alloc((size_t)NN * 512 * 2); // [N][4*128] bf16
  unsigned short* x1h    = (unsigned short*)alloc((size_t)NN * 512 * 2); // [N][512] bf16
  unsigned short* xs2    = (unsigned short*)alloc((size_t)NN * 64 * 2);  // [N][64] bf16
  float* ssrc1 = (float*)alloc((size_t)4 * SROWS * 4);  // head-major [4][SROWS]
  float* sdst1 = (float*)alloc((size_t)4 * SROWS * 4);
  float* ssrc2 = (float*)alloc((size_t)SROWS * 4);
  float* sdst2 = (float*)alloc((size_t)SROWS * 4);
  int* cnt    = (int*)alloc((size_t)NN * 4);
  int* rowptr = (int*)alloc((size_t)(NN + 1) * 4);
  int* fill   = (int*)alloc((size_t)NN * 4);
  int* csr    = (int*)alloc((size_t)ETOT * 4);
  int* p1     = (int*)alloc((size_t)NSCAN * 4 + 256);
  int* p2     = (int*)alloc((size_t)NSCAN * 4 + 256);
  // layer-1 B: tiled [4][16][144][8] bf16 (cols 0-127 = W, 128/129 = W@att_s/d)
  size_t b1elems = (size_t)4 * 16 * 144 * 8;
  unsigned short* Bh1 = (unsigned short*)alloc(b1elems * 2);
  unsigned short* Bl1 = (unsigned short*)alloc(b1elems * 2);
  unsigned short* Bh2 = (unsigned short*)alloc((size_t)512 * 64 * 2);
  unsigned short* Bl2 = (unsigned short*)alloc((size_t)512 * 64 * 2);

  // ---- CSR build (dst-sorted) ----
  hipMemsetAsync(cnt, 0, (size_t)NN * 4, stream);
  hipMemsetAsync(fill, 0, (size_t)NN * 4, stream);
  hipMemsetAsync(Bh1, 0, b1elems * 2, stream);
  hipMemsetAsync(Bl1, 0, b1elems * 2, stream);
  k_hist<<<(ETOT + 255) / 256, 256, 0, stream>>>(edge + EE, cnt);
  k_scan1<<<NSCAN, 256, 0, stream>>>(cnt, p1);
  k_scan2<<<1, 64, 0, stream>>>(p1, p2);
  k_scan3<<<NSCAN, 256, 0, stream>>>(cnt, p2, rowptr);
  k_scatter<<<(ETOT + 255) / 256, 256, 0, stream>>>(edge, edge + EE, rowptr, fill, csr);

  // ---- weight conversion ----
  k_convB<<<(4 * 128 * 128 + 255) / 256, 256, 0, stream>>>(W, Bh1, Bl1, 128, 128, 144, 4 * 128 * 128);
  k_convAtt<<<4, 128, 0, stream>>>(W, att_src, att_dst, Bh1, Bl1, 128, 128, 144);
  k_convB<<<(512 * 64 + 255) / 256, 256, 0, stream>>>(W_out, Bh2, Bl2, 512, 64, 64, 512 * 64);

  // ---- layer 1: all 4 heads (GEMM with folded att columns) ----
  gemm_split<128, 144, 512><<<dim3(391, 4), 256, 0, stream>>>(
      type_emb, Bh1, Bl1, xs_all, NN, 128, ssrc1, sdst1);
  k_agg1<<<dim3(3125, 4), 256, 0, stream>>>(rowptr, csr, ssrc1, sdst1, xs_all, bias, x1h);

  // ---- layer 2 (bf16 A, split B) ----
  gemm_ps<64, 64><<<dim3(391, 1), 256, 0, stream>>>(
      x1h, Bh2, Bl2, xs2, NN, 512, att_src_o, att_dst_o, ssrc2, sdst2);
  k_agg2<<<1563, 256, 0, stream>>>(rowptr, csr, ssrc2, sdst2, xs2, bias_o, out);
}

// Round 13
// 440.031 us; speedup vs baseline: 1.0370x; 1.0370x over previous
//
#include <hip/hip_runtime.h>
#include <cmath>

#define NN 50000
#define EE 800000
#define ETOT (EE + NN)
#define NSCAN ((NN + 1023) / 1024)
#define SROWS 50048   // padded rows for head-major logit arrays

typedef __bf16 v8bf __attribute__((ext_vector_type(8)));
typedef float f32x4 __attribute__((ext_vector_type(4)));
typedef float f32x2 __attribute__((ext_vector_type(2)));

__device__ __forceinline__ float lrelu(float x){ return x > 0.0f ? x : 0.2f * x; }
__device__ __forceinline__ unsigned short f2bf_rne(float x){
  unsigned int u = __float_as_uint(x);
  u += 0x7fffu + ((u >> 16) & 1u);
  return (unsigned short)(u >> 16);
}
__device__ __forceinline__ float bf2f(unsigned short b){
  return __uint_as_float(((unsigned int)b) << 16);
}
// packed accumulate: acc[4] of float2 -> v_pk_fma_f32
__device__ __forceinline__ void fma8p(f32x2* acc, float w, uint4 u){
  f32x2 w2 = {w, w};
  f32x2 a0, a1, a2, a3;
  a0[0] = __uint_as_float(u.x << 16); a0[1] = __uint_as_float(u.x & 0xffff0000u);
  a1[0] = __uint_as_float(u.y << 16); a1[1] = __uint_as_float(u.y & 0xffff0000u);
  a2[0] = __uint_as_float(u.z << 16); a2[1] = __uint_as_float(u.z & 0xffff0000u);
  a3[0] = __uint_as_float(u.w << 16); a3[1] = __uint_as_float(u.w & 0xffff0000u);
  acc[0] += w2 * a0;
  acc[1] += w2 * a1;
  acc[2] += w2 * a2;
  acc[3] += w2 * a3;
}

// ---------------- CSR build ----------------
__global__ void k_hist(const int* __restrict__ dst, int* __restrict__ cnt){
  int i = blockIdx.x * 256 + threadIdx.x;
  if (i >= ETOT) return;
  int d = (i < EE) ? dst[i] : (i - EE);
  atomicAdd(&cnt[d], 1);
}

__global__ void k_scan1(const int* __restrict__ cnt, int* __restrict__ part){
  __shared__ int sm[256];
  int b = blockIdx.x, t = threadIdx.x;
  int base = b * 1024 + t * 4;
  int s = 0;
  #pragma unroll
  for (int j = 0; j < 4; j++) if (base + j < NN) s += cnt[base + j];
  sm[t] = s; __syncthreads();
  for (int off = 128; off; off >>= 1){
    if (t < off) sm[t] += sm[t + off];
    __syncthreads();
  }
  if (t == 0) part[b] = sm[0];
}

__global__ void k_scan2(const int* __restrict__ part, int* __restrict__ part2){
  if (threadIdx.x == 0 && blockIdx.x == 0){
    int run = 0;
    for (int i = 0; i < NSCAN; i++){ part2[i] = run; run += part[i]; }
  }
}

__global__ void k_scan3(const int* __restrict__ cnt, const int* __restrict__ part2,
                        int* __restrict__ rowptr){
  __shared__ int sm[256];
  int b = blockIdx.x, t = threadIdx.x;
  int base = b * 1024 + t * 4;
  int v[4]; int s = 0;
  #pragma unroll
  for (int j = 0; j < 4; j++){ v[j] = (base + j < NN) ? cnt[base + j] : 0; s += v[j]; }
  sm[t] = s; __syncthreads();
  for (int off = 1; off < 256; off <<= 1){
    int x = (t >= off) ? sm[t - off] : 0;
    __syncthreads();
    sm[t] += x;
    __syncthreads();
  }
  int run = part2[b] + sm[t] - s;
  #pragma unroll
  for (int j = 0; j < 4; j++){
    if (base + j < NN){ rowptr[base + j] = run; run += v[j]; }
  }
  if (b == 0 && t == 0) rowptr[NN] = ETOT;
}

__global__ void k_scatter(const int* __restrict__ src, const int* __restrict__ dst,
                          const int* __restrict__ rowptr, int* __restrict__ fill,
                          int* __restrict__ csr){
  int i = blockIdx.x * 256 + threadIdx.x;
  if (i >= ETOT) return;
  int s, d;
  if (i < EE){ s = src[i]; d = dst[i]; } else { s = d = i - EE; }
  int pos = rowptr[d] + atomicAdd(&fill[d], 1);
  csr[pos] = s;
}

// ---------------- weight conversion: fp32 [.,K,N] -> bf16 hi/lo [.,K/8,N,8] ----
__global__ void k_convB(const float* __restrict__ B, unsigned short* __restrict__ bh,
                        unsigned short* __restrict__ bl, int K, int N, int total){
  int i = blockIdx.x * 256 + threadIdx.x;
  if (i >= total) return;
  int per = K * N;
  int h = i / per, rem = i - h * per;
  int k = rem / N, n = rem - k * N;
  float x = B[i];
  unsigned short hb = f2bf_rne(x);
  unsigned short lb = f2bf_rne(x - bf2f(hb));
  size_t o = (size_t)h * per + ((size_t)(k >> 3) * N + n) * 8 + (k & 7);
  bh[o] = hb; bl[o] = lb;
}

// ---------------- layer-1 GEMM: A single bf16 (staged from fp32), B split ----
// Round-12 proved single-bf16 A leaves absmax bit-identical; keep B hi/lo.
// 2 MFMA per (rt,ct); fused att row-dots in the epilogue (shuffle reduce).
template<int BN, int OSTR>
__global__ __launch_bounds__(256) void gemm_split(const float* __restrict__ A,
                                                  const unsigned short* __restrict__ Bh,
                                                  const unsigned short* __restrict__ Bl,
                                                  unsigned short* __restrict__ out,
                                                  int M, int K,
                                                  const float* __restrict__ att_s,
                                                  const float* __restrict__ att_d,
                                                  float* __restrict__ ssrc,
                                                  float* __restrict__ sdst){
  const int t = threadIdx.x;
  const int wv = t >> 6, lane = t & 63;
  const int m0 = blockIdx.x * 128;
  const int h = blockIdx.y;
  A  += (size_t)h * M * K;
  Bh += (size_t)h * (K >> 3) * BN * 8;
  Bl += (size_t)h * (K >> 3) * BN * 8;
  const int colOff = h * BN;

  __shared__ v8bf sA[4][128];
  __shared__ v8bf sBh[4][BN];
  __shared__ v8bf sBl[4][BN];

  f32x4 acc[2][BN / 16];
  #pragma unroll
  for (int i = 0; i < 2; i++)
    #pragma unroll
    for (int j = 0; j < BN / 16; j++){
      f32x4 z = {0.f, 0.f, 0.f, 0.f};
      acc[i][j] = z;
    }

  const int mRow = t & 127;
  const int kh = (t >> 7) * 16;
  const bool valid = (m0 + mRow) < M;
  const int q = lane >> 4, lm = lane & 15;

  for (int k0 = 0; k0 < K; k0 += 32){
    const float* ap = A + (size_t)(m0 + mRow) * K + k0 + kh;
    float4 v0, v1, v2, v3;
    if (valid){
      v0 = *(const float4*)(ap);
      v1 = *(const float4*)(ap + 4);
      v2 = *(const float4*)(ap + 8);
      v3 = *(const float4*)(ap + 12);
    } else {
      v0 = v1 = v2 = v3 = make_float4(0.f, 0.f, 0.f, 0.f);
    }
    #pragma unroll
    for (int g = 0; g < 2; g++){
      float xv[8];
      if (g == 0){ xv[0]=v0.x; xv[1]=v0.y; xv[2]=v0.z; xv[3]=v0.w; xv[4]=v1.x; xv[5]=v1.y; xv[6]=v1.z; xv[7]=v1.w; }
      else       { xv[0]=v2.x; xv[1]=v2.y; xv[2]=v2.z; xv[3]=v2.w; xv[4]=v3.x; xv[5]=v3.y; xv[6]=v3.z; xv[7]=v3.w; }
      v8bf H;
      #pragma unroll
      for (int i = 0; i < 8; i++) H[i] = (__bf16)xv[i];   // v_cvt_pk_bf16_f32, RNE
      sA[(kh >> 3) + g][mRow] = H;
    }
    {
      const v8bf* gh = (const v8bf*)Bh + (size_t)(k0 >> 3) * BN;
      const v8bf* gl = (const v8bf*)Bl + (size_t)(k0 >> 3) * BN;
      v8bf* dh = &sBh[0][0];
      v8bf* dl = &sBl[0][0];
      #pragma unroll
      for (int i = t; i < 4 * BN; i += 256){ dh[i] = gh[i]; dl[i] = gl[i]; }
    }
    __syncthreads();
    v8bf ah[2];
    #pragma unroll
    for (int rt = 0; rt < 2; rt++)
      ah[rt] = sA[q][wv * 32 + rt * 16 + lm];
    #pragma unroll
    for (int ct = 0; ct < BN / 16; ct++){
      v8bf bh = sBh[q][ct * 16 + lm];
      v8bf bl = sBl[q][ct * 16 + lm];
      #pragma unroll
      for (int rt = 0; rt < 2; rt++){
        acc[rt][ct] = __builtin_amdgcn_mfma_f32_16x16x32_bf16(ah[rt], bh, acc[rt][ct], 0, 0, 0);
        acc[rt][ct] = __builtin_amdgcn_mfma_f32_16x16x32_bf16(ah[rt], bl, acc[rt][ct], 0, 0, 0);
      }
    }
    __syncthreads();
  }

  float asv[BN / 16], adv[BN / 16];
  #pragma unroll
  for (int ct = 0; ct < BN / 16; ct++){
    asv[ct] = att_s[h * BN + ct * 16 + lm];
    adv[ct] = att_d[h * BN + ct * 16 + lm];
  }

  #pragma unroll
  for (int rt = 0; rt < 2; rt++){
    #pragma unroll
    for (int reg = 0; reg < 4; reg++){
      int r = m0 + wv * 32 + rt * 16 + q * 4 + reg;
      float d0 = 0.f, d1 = 0.f;
      #pragma unroll
      for (int ct = 0; ct < BN / 16; ct++){
        float v = acc[rt][ct][reg];
        d0 += v * asv[ct];
        d1 += v * adv[ct];
      }
      #pragma unroll
      for (int off = 1; off < 16; off <<= 1){
        d0 += __shfl_xor(d0, off, 64);
        d1 += __shfl_xor(d1, off, 64);
      }
      if (r < M){
        unsigned short* orow = out + (size_t)r * OSTR + colOff + lm;
        #pragma unroll
        for (int ct = 0; ct < BN / 16; ct++)
          orow[ct * 16] = f2bf_rne(acc[rt][ct][reg]);
        if (lm == 0){
          ssrc[(size_t)h * SROWS + r] = d0;
          sdst[(size_t)h * SROWS + r] = d1;
        }
      }
    }
  }
}

// ---------------- layer-2 GEMM (A single bf16, B split hi/lo) ---------------
template<int BN, int OSTR>
__global__ __launch_bounds__(256) void gemm_ps(const unsigned short* __restrict__ Ah,
                                               const unsigned short* __restrict__ Bh,
                                               const unsigned short* __restrict__ Bl,
                                               unsigned short* __restrict__ out,
                                               int M, int K,
                                               const float* __restrict__ att_s,
                                               const float* __restrict__ att_d,
                                               float* __restrict__ ssrc,
                                               float* __restrict__ sdst){
  const int t = threadIdx.x;
  const int wv = t >> 6, lane = t & 63;
  const int m0 = blockIdx.x * 128;
  const int h = blockIdx.y;
  const int colOff = h * BN;

  __shared__ v8bf sAh[4][128];
  __shared__ v8bf sBh[4][BN];
  __shared__ v8bf sBl[4][BN];

  f32x4 acc[2][BN / 16];
  #pragma unroll
  for (int i = 0; i < 2; i++)
    #pragma unroll
    for (int j = 0; j < BN / 16; j++){
      f32x4 z = {0.f, 0.f, 0.f, 0.f};
      acc[i][j] = z;
    }

  const int mRow = t & 127;
  const int kh = (t >> 7) * 16;
  const bool valid = (m0 + mRow) < M;
  const int q = lane >> 4, lm = lane & 15;

  for (int k0 = 0; k0 < K; k0 += 32){
    // ---- stage A: pure 16B copies ----
    const unsigned short* aph = Ah + (size_t)(m0 + mRow) * K + k0 + kh;
    uint4 h0, h1;
    if (valid){
      h0 = *(const uint4*)(aph);
      h1 = *(const uint4*)(aph + 8);
    } else {
      h0 = h1 = make_uint4(0, 0, 0, 0);
    }
    int k8 = kh >> 3;
    sAh[k8][mRow]     = *(v8bf*)&h0;
    sAh[k8 + 1][mRow] = *(v8bf*)&h1;
    {
      const v8bf* gh = (const v8bf*)Bh + (size_t)(k0 >> 3) * BN;
      const v8bf* gl = (const v8bf*)Bl + (size_t)(k0 >> 3) * BN;
      v8bf* dh = &sBh[0][0];
      v8bf* dl = &sBl[0][0];
      #pragma unroll
      for (int i = t; i < 4 * BN; i += 256){ dh[i] = gh[i]; dl[i] = gl[i]; }
    }
    __syncthreads();
    v8bf ah[2];
    #pragma unroll
    for (int rt = 0; rt < 2; rt++){
      int m = wv * 32 + rt * 16 + lm;
      ah[rt] = sAh[q][m];
    }
    #pragma unroll
    for (int ct = 0; ct < BN / 16; ct++){
      v8bf bh = sBh[q][ct * 16 + lm];
      v8bf bl = sBl[q][ct * 16 + lm];
      #pragma unroll
      for (int rt = 0; rt < 2; rt++){
        acc[rt][ct] = __builtin_amdgcn_mfma_f32_16x16x32_bf16(ah[rt], bh, acc[rt][ct], 0, 0, 0);
        acc[rt][ct] = __builtin_amdgcn_mfma_f32_16x16x32_bf16(ah[rt], bl, acc[rt][ct], 0, 0, 0);
      }
    }
    __syncthreads();
  }

  float asv[BN / 16], adv[BN / 16];
  #pragma unroll
  for (int ct = 0; ct < BN / 16; ct++){
    asv[ct] = att_s[h * BN + ct * 16 + lm];
    adv[ct] = att_d[h * BN + ct * 16 + lm];
  }

  #pragma unroll
  for (int rt = 0; rt < 2; rt++){
    #pragma unroll
    for (int reg = 0; reg < 4; reg++){
      int r = m0 + wv * 32 + rt * 16 + q * 4 + reg;
      float d0 = 0.f, d1 = 0.f;
      #pragma unroll
      for (int ct = 0; ct < BN / 16; ct++){
        float v = acc[rt][ct][reg];
        d0 += v * asv[ct];
        d1 += v * adv[ct];
      }
      #pragma unroll
      for (int off = 1; off < 16; off <<= 1){
        d0 += __shfl_xor(d0, off, 64);
        d1 += __shfl_xor(d1, off, 64);
      }
      if (r < M){
        unsigned short* orow = out + (size_t)r * OSTR + colOff + lm;
        #pragma unroll
        for (int ct = 0; ct < BN / 16; ct++)
          orow[ct * 16] = f2bf_rne(acc[rt][ct][reg]);
        if (lm == 0){
          ssrc[(size_t)h * SROWS + r] = d0;
          sdst[(size_t)h * SROWS + r] = d1;
        }
      }
    }
  }
}

// ---------------- layer-1 aggregation: 16-lane group per (node, head) --------
// Round-4/9 structure (proven locality optimum): per-head grid.y (12.8MB hot
// slice), 4 nodes/wave, no shuffles (same-address broadcast of csr/ssrc),
// depth-2 pipeline, packed v_pk_fma_f32. x1 written as SINGLE bf16 (hi only).
__global__ __launch_bounds__(256) void k_agg1(const int* __restrict__ rowptr,
                                              const int* __restrict__ csr,
                                              const float* __restrict__ ssrc,
                                              const float* __restrict__ sdst,
                                              const unsigned short* __restrict__ xs_all,
                                              const float* __restrict__ bias,
                                              unsigned short* __restrict__ x1h){
  int tid = blockIdx.x * 256 + threadIdx.x;
  int n = tid >> 4;
  int lm = threadIdx.x & 15;
  int h = blockIdx.y;
  if (n >= NN) return;
  int start = rowptr[n], end = rowptr[n + 1];
  const float* sp = ssrc + (size_t)h * SROWS;
  float sdn = sdst[(size_t)h * SROWS + n];
  const uint4* xp = (const uint4*)xs_all + h * 16 + lm;

  float sloc = 0.f;
  f32x2 acc[4];
  #pragma unroll
  for (int i = 0; i < 4; i++){ f32x2 z = {0.f, 0.f}; acc[i] = z; }

  // depth-2 pipeline: consume edge e while loading e+1
  int e = start;
  int sA = csr[e];
  float svA = sp[sA];
  uint4 uA = xp[(size_t)sA * 64];
  for (; e + 1 < end; e++){
    int sB = csr[e + 1];
    float svB = sp[sB];
    uint4 uB = xp[(size_t)sB * 64];
    float w = __expf(lrelu(svA + sdn));
    sloc += w;
    fma8p(acc, w, uA);
    svA = svB; uA = uB;
  }
  float w = __expf(lrelu(svA + sdn));
  sloc += w;
  fma8p(acc, w, uA);

  float inv = 1.f / sloc;

  const float* bp = bias + h * 128 + lm * 8;
  float4 b0 = *(const float4*)bp, b1 = *(const float4*)(bp + 4);
  float bb[8] = {b0.x, b0.y, b0.z, b0.w, b1.x, b1.y, b1.z, b1.w};
  union { uint4 q; unsigned short u[8]; } HH;
  #pragma unroll
  for (int i = 0; i < 8; i++){
    float o = lrelu(acc[i >> 1][i & 1] * inv + bb[i]);
    HH.u[i] = f2bf_rne(o);
  }
  size_t ofs = (size_t)n * 512 + h * 128 + lm * 8;
  *(uint4*)(x1h + ofs) = HH.q;
}

// ---------------- layer-2 aggregation: 8-lane group per node ------------------
// Round-4/9 structure + packed fma. sloc is full denominator per-lane.
__global__ __launch_bounds__(256) void k_agg2(const int* __restrict__ rowptr,
                                              const int* __restrict__ csr,
                                              const float* __restrict__ ssrc,
                                              const float* __restrict__ sdst,
                                              const unsigned short* __restrict__ xs2,
                                              const float* __restrict__ bias,
                                              float* __restrict__ outp){
  int tid = blockIdx.x * 256 + threadIdx.x;
  int n = tid >> 3;
  int lm = threadIdx.x & 7;
  if (n >= NN) return;
  int start = rowptr[n], end = rowptr[n + 1];
  float sdn = sdst[n];
  const uint4* xp = (const uint4*)xs2 + lm;

  float sloc = 0.f;
  f32x2 acc[4];
  #pragma unroll
  for (int i = 0; i < 4; i++){ f32x2 z = {0.f, 0.f}; acc[i] = z; }

  int e = start;
  int sA = csr[e];
  float svA = ssrc[sA];
  uint4 uA = xp[(size_t)sA * 8];
  for (; e + 1 < end; e++){
    int sB = csr[e + 1];
    float svB = ssrc[sB];
    uint4 uB = xp[(size_t)sB * 8];
    float w = __expf(lrelu(svA + sdn));
    sloc += w;
    fma8p(acc, w, uA);
    svA = svB; uA = uB;
  }
  float w = __expf(lrelu(svA + sdn));
  sloc += w;
  fma8p(acc, w, uA);

  float inv = 1.f / sloc;

  float o[8];
  #pragma unroll
  for (int i = 0; i < 8; i++)
    o[i] = tanhf(lrelu(acc[i >> 1][i & 1] * inv + bias[lm * 8 + i]));
  float* op = outp + (size_t)n * 64 + lm * 8;
  *(float4*)op       = make_float4(o[0], o[1], o[2], o[3]);
  *(float4*)(op + 4) = make_float4(o[4], o[5], o[6], o[7]);
}

extern "C" void kernel_launch(void* const* d_in, const int* in_sizes, int n_in,
                              void* d_out, int out_size, void* d_ws, size_t ws_size,
                              hipStream_t stream){
  const float* type_emb  = (const float*)d_in[0];
  const int*   edge      = (const int*)d_in[1];
  const float* W         = (const float*)d_in[2];
  const float* att_src   = (const float*)d_in[3];
  const float* att_dst   = (const float*)d_in[4];
  const float* bias      = (const float*)d_in[5];
  const float* W_out     = (const float*)d_in[6];
  const float* att_src_o = (const float*)d_in[7];
  const float* att_dst_o = (const float*)d_in[8];
  const float* bias_o    = (const float*)d_in[9];
  float* out = (float*)d_out;
  (void)in_sizes; (void)n_in; (void)out_size; (void)ws_size;

  char* ws = (char*)d_ws;
  size_t off = 0;
  auto alloc = [&](size_t bytes) -> void* {
    void* p = ws + off;
    off = (off + bytes + 255) & ~(size_t)255;
    return p;
  };
  unsigned short* xs_all = (unsigned short*)alloc((size_t)NN * 512 * 2); // [N][4*128] bf16
  unsigned short* x1h    = (unsigned short*)alloc((size_t)NN * 512 * 2); // [N][512] bf16
  unsigned short* xs2    = (unsigned short*)alloc((size_t)NN * 64 * 2);  // [N][64] bf16
  float* ssrc1 = (float*)alloc((size_t)4 * SROWS * 4);  // head-major [4][SROWS]
  float* sdst1 = (float*)alloc((size_t)4 * SROWS * 4);
  float* ssrc2 = (float*)alloc((size_t)SROWS * 4);
  float* sdst2 = (float*)alloc((size_t)SROWS * 4);
  int* cnt    = (int*)alloc((size_t)NN * 4);
  int* rowptr = (int*)alloc((size_t)(NN + 1) * 4);
  int* fill   = (int*)alloc((size_t)NN * 4);
  int* csr    = (int*)alloc((size_t)ETOT * 4);
  int* p1     = (int*)alloc((size_t)NSCAN * 4 + 256);
  int* p2     = (int*)alloc((size_t)NSCAN * 4 + 256);
  unsigned short* Bh1 = (unsigned short*)alloc((size_t)4 * 128 * 128 * 2);
  unsigned short* Bl1 = (unsigned short*)alloc((size_t)4 * 128 * 128 * 2);
  unsigned short* Bh2 = (unsigned short*)alloc((size_t)512 * 64 * 2);
  unsigned short* Bl2 = (unsigned short*)alloc((size_t)512 * 64 * 2);

  // ---- CSR build (dst-sorted) ----
  hipMemsetAsync(cnt, 0, (size_t)NN * 4, stream);
  hipMemsetAsync(fill, 0, (size_t)NN * 4, stream);
  k_hist<<<(ETOT + 255) / 256, 256, 0, stream>>>(edge + EE, cnt);
  k_scan1<<<NSCAN, 256, 0, stream>>>(cnt, p1);
  k_scan2<<<1, 64, 0, stream>>>(p1, p2);
  k_scan3<<<NSCAN, 256, 0, stream>>>(cnt, p2, rowptr);
  k_scatter<<<(ETOT + 255) / 256, 256, 0, stream>>>(edge, edge + EE, rowptr, fill, csr);

  // ---- weight conversion ----
  k_convB<<<(4 * 128 * 128 + 255) / 256, 256, 0, stream>>>(W, Bh1, Bl1, 128, 128, 4 * 128 * 128);
  k_convB<<<(512 * 64 + 255) / 256, 256, 0, stream>>>(W_out, Bh2, Bl2, 512, 64, 512 * 64);

  // ---- layer 1: all 4 heads (GEMM + fused att row-dots) ----
  gemm_split<128, 512><<<dim3(391, 4), 256, 0, stream>>>(
      type_emb, Bh1, Bl1, xs_all, NN, 128, att_src, att_dst, ssrc1, sdst1);
  k_agg1<<<dim3(3125, 4), 256, 0, stream>>>(rowptr, csr, ssrc1, sdst1, xs_all, bias, x1h);

  // ---- layer 2 (bf16 A, split B) ----
  gemm_ps<64, 64><<<dim3(391, 1), 256, 0, stream>>>(
      x1h, Bh2, Bl2, xs2, NN, 512, att_src_o, att_dst_o, ssrc2, sdst2);
  k_agg2<<<1563, 256, 0, stream>>>(rowptr, csr, ssrc2, sdst2, xs2, bias_o, out);
}

// Round 14
// 435.683 us; speedup vs baseline: 1.0473x; 1.0100x over previous
//
#include <hip/hip_runtime.h>
#include <cmath>

#define NN 50000
#define EE 800000
#define ETOT (EE + NN)
#define NSCAN ((NN + 1023) / 1024)
#define SROWS 50048   // padded rows for head-major logit arrays

typedef __bf16 v8bf __attribute__((ext_vector_type(8)));
typedef float f32x4 __attribute__((ext_vector_type(4)));
typedef float f32x2 __attribute__((ext_vector_type(2)));

__device__ __forceinline__ float lrelu(float x){ return x > 0.0f ? x : 0.2f * x; }
__device__ __forceinline__ unsigned short f2bf_rne(float x){
  unsigned int u = __float_as_uint(x);
  u += 0x7fffu + ((u >> 16) & 1u);
  return (unsigned short)(u >> 16);
}
__device__ __forceinline__ float bf2f(unsigned short b){
  return __uint_as_float(((unsigned int)b) << 16);
}
// async global->LDS, 16B per lane. LDS dest = uniform base + lane*16;
// global src is per-lane.
__device__ __forceinline__ void async_ld16(const void* g, void* l){
  __builtin_amdgcn_global_load_lds(
      (const __attribute__((address_space(1))) unsigned int*)g,
      (__attribute__((address_space(3))) unsigned int*)l, 16, 0, 0);
}
// packed accumulate: acc[4] of float2 -> v_pk_fma_f32
__device__ __forceinline__ void fma8p(f32x2* acc, float w, uint4 u){
  f32x2 w2 = {w, w};
  f32x2 a0, a1, a2, a3;
  a0[0] = __uint_as_float(u.x << 16); a0[1] = __uint_as_float(u.x & 0xffff0000u);
  a1[0] = __uint_as_float(u.y << 16); a1[1] = __uint_as_float(u.y & 0xffff0000u);
  a2[0] = __uint_as_float(u.z << 16); a2[1] = __uint_as_float(u.z & 0xffff0000u);
  a3[0] = __uint_as_float(u.w << 16); a3[1] = __uint_as_float(u.w & 0xffff0000u);
  acc[0] += w2 * a0;
  acc[1] += w2 * a1;
  acc[2] += w2 * a2;
  acc[3] += w2 * a3;
}

// ---------------- CSR build ----------------
__global__ void k_hist(const int* __restrict__ dst, int* __restrict__ cnt){
  int i = blockIdx.x * 256 + threadIdx.x;
  if (i >= ETOT) return;
  int d = (i < EE) ? dst[i] : (i - EE);
  atomicAdd(&cnt[d], 1);
}

__global__ void k_scan1(const int* __restrict__ cnt, int* __restrict__ part){
  __shared__ int sm[256];
  int b = blockIdx.x, t = threadIdx.x;
  int base = b * 1024 + t * 4;
  int s = 0;
  #pragma unroll
  for (int j = 0; j < 4; j++) if (base + j < NN) s += cnt[base + j];
  sm[t] = s; __syncthreads();
  for (int off = 128; off; off >>= 1){
    if (t < off) sm[t] += sm[t + off];
    __syncthreads();
  }
  if (t == 0) part[b] = sm[0];
}

__global__ void k_scan2(const int* __restrict__ part, int* __restrict__ part2){
  if (threadIdx.x == 0 && blockIdx.x == 0){
    int run = 0;
    for (int i = 0; i < NSCAN; i++){ part2[i] = run; run += part[i]; }
  }
}

__global__ void k_scan3(const int* __restrict__ cnt, const int* __restrict__ part2,
                        int* __restrict__ rowptr){
  __shared__ int sm[256];
  int b = blockIdx.x, t = threadIdx.x;
  int base = b * 1024 + t * 4;
  int v[4]; int s = 0;
  #pragma unroll
  for (int j = 0; j < 4; j++){ v[j] = (base + j < NN) ? cnt[base + j] : 0; s += v[j]; }
  sm[t] = s; __syncthreads();
  for (int off = 1; off < 256; off <<= 1){
    int x = (t >= off) ? sm[t - off] : 0;
    __syncthreads();
    sm[t] += x;
    __syncthreads();
  }
  int run = part2[b] + sm[t] - s;
  #pragma unroll
  for (int j = 0; j < 4; j++){
    if (base + j < NN){ rowptr[base + j] = run; run += v[j]; }
  }
  if (b == 0 && t == 0) rowptr[NN] = ETOT;
}

__global__ void k_scatter(const int* __restrict__ src, const int* __restrict__ dst,
                          const int* __restrict__ rowptr, int* __restrict__ fill,
                          int* __restrict__ csr){
  int i = blockIdx.x * 256 + threadIdx.x;
  if (i >= ETOT) return;
  int s, d;
  if (i < EE){ s = src[i]; d = dst[i]; } else { s = d = i - EE; }
  int pos = rowptr[d] + atomicAdd(&fill[d], 1);
  csr[pos] = s;
}

// ---------------- weight conversion: fp32 [.,K,N] -> bf16 hi/lo [.,K/8,N,8] ----
__global__ void k_convB(const float* __restrict__ B, unsigned short* __restrict__ bh,
                        unsigned short* __restrict__ bl, int K, int N, int total){
  int i = blockIdx.x * 256 + threadIdx.x;
  if (i >= total) return;
  int per = K * N;
  int h = i / per, rem = i - h * per;
  int k = rem / N, n = rem - k * N;
  float x = B[i];
  unsigned short hb = f2bf_rne(x);
  unsigned short lb = f2bf_rne(x - bf2f(hb));
  size_t o = (size_t)h * per + ((size_t)(k >> 3) * N + n) * 8 + (k & 7);
  bh[o] = hb; bl[o] = lb;
}

// ---------------- layer-1 GEMM: A single bf16 (staged from fp32), B split ----
// B staged via async global_load_lds (16B/lane); A converts in-flight (VGPR).
template<int BN, int OSTR>
__global__ __launch_bounds__(256) void gemm_split(const float* __restrict__ A,
                                                  const unsigned short* __restrict__ Bh,
                                                  const unsigned short* __restrict__ Bl,
                                                  unsigned short* __restrict__ out,
                                                  int M, int K,
                                                  const float* __restrict__ att_s,
                                                  const float* __restrict__ att_d,
                                                  float* __restrict__ ssrc,
                                                  float* __restrict__ sdst){
  const int t = threadIdx.x;
  const int wv = t >> 6, lane = t & 63;
  const int m0 = blockIdx.x * 128;
  const int h = blockIdx.y;
  A  += (size_t)h * M * K;
  Bh += (size_t)h * (K >> 3) * BN * 8;
  Bl += (size_t)h * (K >> 3) * BN * 8;
  const int colOff = h * BN;

  __shared__ v8bf sA[4][128];
  __shared__ v8bf sBh[4][BN];
  __shared__ v8bf sBl[4][BN];

  f32x4 acc[2][BN / 16];
  #pragma unroll
  for (int i = 0; i < 2; i++)
    #pragma unroll
    for (int j = 0; j < BN / 16; j++){
      f32x4 z = {0.f, 0.f, 0.f, 0.f};
      acc[i][j] = z;
    }

  const int mRow = t & 127;
  const int kh = (t >> 7) * 16;
  const bool valid = (m0 + mRow) < M;
  const int q = lane >> 4, lm = lane & 15;

  for (int k0 = 0; k0 < K; k0 += 32){
    // ---- stage B: async global->LDS, one 1KB wave-chunk per issue ----
    {
      const uint4* gh = (const uint4*)((const v8bf*)Bh + (size_t)(k0 >> 3) * BN);
      const uint4* gl = (const uint4*)((const v8bf*)Bl + (size_t)(k0 >> 3) * BN);
      uint4* dh = (uint4*)&sBh[0][0];
      uint4* dl = (uint4*)&sBl[0][0];
      constexpr int NCH = (4 * BN) / 64;
      #pragma unroll
      for (int c = wv; c < NCH; c += 4){
        async_ld16(gh + c * 64 + lane, dh + c * 64);
        async_ld16(gl + c * 64 + lane, dl + c * 64);
      }
    }
    // ---- stage A (fp32 -> bf16 in VGPRs) ----
    const float* ap = A + (size_t)(m0 + mRow) * K + k0 + kh;
    float4 v0, v1, v2, v3;
    if (valid){
      v0 = *(const float4*)(ap);
      v1 = *(const float4*)(ap + 4);
      v2 = *(const float4*)(ap + 8);
      v3 = *(const float4*)(ap + 12);
    } else {
      v0 = v1 = v2 = v3 = make_float4(0.f, 0.f, 0.f, 0.f);
    }
    #pragma unroll
    for (int g = 0; g < 2; g++){
      float xv[8];
      if (g == 0){ xv[0]=v0.x; xv[1]=v0.y; xv[2]=v0.z; xv[3]=v0.w; xv[4]=v1.x; xv[5]=v1.y; xv[6]=v1.z; xv[7]=v1.w; }
      else       { xv[0]=v2.x; xv[1]=v2.y; xv[2]=v2.z; xv[3]=v2.w; xv[4]=v3.x; xv[5]=v3.y; xv[6]=v3.z; xv[7]=v3.w; }
      v8bf H;
      #pragma unroll
      for (int i = 0; i < 8; i++) H[i] = (__bf16)xv[i];   // v_cvt_pk_bf16_f32, RNE
      sA[(kh >> 3) + g][mRow] = H;
    }
    __syncthreads();
    v8bf ah[2];
    #pragma unroll
    for (int rt = 0; rt < 2; rt++)
      ah[rt] = sA[q][wv * 32 + rt * 16 + lm];
    #pragma unroll
    for (int ct = 0; ct < BN / 16; ct++){
      v8bf bh = sBh[q][ct * 16 + lm];
      v8bf bl = sBl[q][ct * 16 + lm];
      #pragma unroll
      for (int rt = 0; rt < 2; rt++){
        acc[rt][ct] = __builtin_amdgcn_mfma_f32_16x16x32_bf16(ah[rt], bh, acc[rt][ct], 0, 0, 0);
        acc[rt][ct] = __builtin_amdgcn_mfma_f32_16x16x32_bf16(ah[rt], bl, acc[rt][ct], 0, 0, 0);
      }
    }
    __syncthreads();
  }

  float asv[BN / 16], adv[BN / 16];
  #pragma unroll
  for (int ct = 0; ct < BN / 16; ct++){
    asv[ct] = att_s[h * BN + ct * 16 + lm];
    adv[ct] = att_d[h * BN + ct * 16 + lm];
  }

  #pragma unroll
  for (int rt = 0; rt < 2; rt++){
    #pragma unroll
    for (int reg = 0; reg < 4; reg++){
      int r = m0 + wv * 32 + rt * 16 + q * 4 + reg;
      float d0 = 0.f, d1 = 0.f;
      #pragma unroll
      for (int ct = 0; ct < BN / 16; ct++){
        float v = acc[rt][ct][reg];
        d0 += v * asv[ct];
        d1 += v * adv[ct];
      }
      #pragma unroll
      for (int off = 1; off < 16; off <<= 1){
        d0 += __shfl_xor(d0, off, 64);
        d1 += __shfl_xor(d1, off, 64);
      }
      if (r < M){
        unsigned short* orow = out + (size_t)r * OSTR + colOff + lm;
        #pragma unroll
        for (int ct = 0; ct < BN / 16; ct++)
          orow[ct * 16] = f2bf_rne(acc[rt][ct][reg]);
        if (lm == 0){
          ssrc[(size_t)h * SROWS + r] = d0;
          sdst[(size_t)h * SROWS + r] = d1;
        }
      }
    }
  }
}

// ---------------- layer-2 GEMM (A single bf16, B split hi/lo) ---------------
// A and B staged via async global_load_lds. A rows >= M read stale/garbage
// data (within workspace, no fault) that only feeds output rows >= M which
// are never stored.
template<int BN, int OSTR>
__global__ __launch_bounds__(256) void gemm_ps(const unsigned short* __restrict__ Ah,
                                               const unsigned short* __restrict__ Bh,
                                               const unsigned short* __restrict__ Bl,
                                               unsigned short* __restrict__ out,
                                               int M, int K,
                                               const float* __restrict__ att_s,
                                               const float* __restrict__ att_d,
                                               float* __restrict__ ssrc,
                                               float* __restrict__ sdst){
  const int t = threadIdx.x;
  const int wv = t >> 6, lane = t & 63;
  const int m0 = blockIdx.x * 128;
  const int h = blockIdx.y;
  const int colOff = h * BN;

  __shared__ v8bf sAh[4][128];
  __shared__ v8bf sBh[4][BN];
  __shared__ v8bf sBl[4][BN];

  f32x4 acc[2][BN / 16];
  #pragma unroll
  for (int i = 0; i < 2; i++)
    #pragma unroll
    for (int j = 0; j < BN / 16; j++){
      f32x4 z = {0.f, 0.f, 0.f, 0.f};
      acc[i][j] = z;
    }

  const int mRow = t & 127;
  const int kh = (t >> 7) * 16;
  const int k8 = kh >> 3;
  const int q = lane >> 4, lm = lane & 15;

  for (int k0 = 0; k0 < K; k0 += 32){
    // ---- stage A: async, wave-uniform LDS base + per-lane row-strided src ----
    {
      const unsigned short* aph = Ah + (size_t)(m0 + mRow) * K + k0 + kh;
      uint4* base0 = (uint4*)&sAh[k8][(wv & 1) * 64];
      uint4* base1 = (uint4*)&sAh[k8 + 1][(wv & 1) * 64];
      async_ld16(aph, base0);
      async_ld16(aph + 8, base1);
    }
    // ---- stage B: async ----
    {
      const uint4* gh = (const uint4*)((const v8bf*)Bh + (size_t)(k0 >> 3) * BN);
      const uint4* gl = (const uint4*)((const v8bf*)Bl + (size_t)(k0 >> 3) * BN);
      uint4* dh = (uint4*)&sBh[0][0];
      uint4* dl = (uint4*)&sBl[0][0];
      constexpr int NCH = (4 * BN) / 64;
      #pragma unroll
      for (int c = wv; c < NCH; c += 4){
        async_ld16(gh + c * 64 + lane, dh + c * 64);
        async_ld16(gl + c * 64 + lane, dl + c * 64);
      }
    }
    __syncthreads();
    v8bf ah[2];
    #pragma unroll
    for (int rt = 0; rt < 2; rt++){
      int m = wv * 32 + rt * 16 + lm;
      ah[rt] = sAh[q][m];
    }
    #pragma unroll
    for (int ct = 0; ct < BN / 16; ct++){
      v8bf bh = sBh[q][ct * 16 + lm];
      v8bf bl = sBl[q][ct * 16 + lm];
      #pragma unroll
      for (int rt = 0; rt < 2; rt++){
        acc[rt][ct] = __builtin_amdgcn_mfma_f32_16x16x32_bf16(ah[rt], bh, acc[rt][ct], 0, 0, 0);
        acc[rt][ct] = __builtin_amdgcn_mfma_f32_16x16x32_bf16(ah[rt], bl, acc[rt][ct], 0, 0, 0);
      }
    }
    __syncthreads();
  }

  float asv[BN / 16], adv[BN / 16];
  #pragma unroll
  for (int ct = 0; ct < BN / 16; ct++){
    asv[ct] = att_s[h * BN + ct * 16 + lm];
    adv[ct] = att_d[h * BN + ct * 16 + lm];
  }

  #pragma unroll
  for (int rt = 0; rt < 2; rt++){
    #pragma unroll
    for (int reg = 0; reg < 4; reg++){
      int r = m0 + wv * 32 + rt * 16 + q * 4 + reg;
      float d0 = 0.f, d1 = 0.f;
      #pragma unroll
      for (int ct = 0; ct < BN / 16; ct++){
        float v = acc[rt][ct][reg];
        d0 += v * asv[ct];
        d1 += v * adv[ct];
      }
      #pragma unroll
      for (int off = 1; off < 16; off <<= 1){
        d0 += __shfl_xor(d0, off, 64);
        d1 += __shfl_xor(d1, off, 64);
      }
      if (r < M){
        unsigned short* orow = out + (size_t)r * OSTR + colOff + lm;
        #pragma unroll
        for (int ct = 0; ct < BN / 16; ct++)
          orow[ct * 16] = f2bf_rne(acc[rt][ct][reg]);
        if (lm == 0){
          ssrc[(size_t)h * SROWS + r] = d0;
          sdst[(size_t)h * SROWS + r] = d1;
        }
      }
    }
  }
}

// ---------------- layer-1 aggregation: 16-lane group per (node, head) --------
// Round-4/9 structure (proven locality optimum): per-head grid.y (12.8MB hot
// slice), 4 nodes/wave, no shuffles (same-address broadcast of csr/ssrc),
// depth-2 pipeline, packed v_pk_fma_f32. x1 written as SINGLE bf16 (hi only).
__global__ __launch_bounds__(256) void k_agg1(const int* __restrict__ rowptr,
                                              const int* __restrict__ csr,
                                              const float* __restrict__ ssrc,
                                              const float* __restrict__ sdst,
                                              const unsigned short* __restrict__ xs_all,
                                              const float* __restrict__ bias,
                                              unsigned short* __restrict__ x1h){
  int tid = blockIdx.x * 256 + threadIdx.x;
  int n = tid >> 4;
  int lm = threadIdx.x & 15;
  int h = blockIdx.y;
  if (n >= NN) return;
  int start = rowptr[n], end = rowptr[n + 1];
  const float* sp = ssrc + (size_t)h * SROWS;
  float sdn = sdst[(size_t)h * SROWS + n];
  const uint4* xp = (const uint4*)xs_all + h * 16 + lm;

  float sloc = 0.f;
  f32x2 acc[4];
  #pragma unroll
  for (int i = 0; i < 4; i++){ f32x2 z = {0.f, 0.f}; acc[i] = z; }

  // depth-2 pipeline: consume edge e while loading e+1
  int e = start;
  int sA = csr[e];
  float svA = sp[sA];
  uint4 uA = xp[(size_t)sA * 64];
  for (; e + 1 < end; e++){
    int sB = csr[e + 1];
    float svB = sp[sB];
    uint4 uB = xp[(size_t)sB * 64];
    float w = __expf(lrelu(svA + sdn));
    sloc += w;
    fma8p(acc, w, uA);
    svA = svB; uA = uB;
  }
  float w = __expf(lrelu(svA + sdn));
  sloc += w;
  fma8p(acc, w, uA);

  float inv = 1.f / sloc;

  const float* bp = bias + h * 128 + lm * 8;
  float4 b0 = *(const float4*)bp, b1 = *(const float4*)(bp + 4);
  float bb[8] = {b0.x, b0.y, b0.z, b0.w, b1.x, b1.y, b1.z, b1.w};
  union { uint4 q; unsigned short u[8]; } HH;
  #pragma unroll
  for (int i = 0; i < 8; i++){
    float o = lrelu(acc[i >> 1][i & 1] * inv + bb[i]);
    HH.u[i] = f2bf_rne(o);
  }
  size_t ofs = (size_t)n * 512 + h * 128 + lm * 8;
  *(uint4*)(x1h + ofs) = HH.q;
}

// ---------------- layer-2 aggregation: 8-lane group per node ------------------
// Round-4/9 structure + packed fma. sloc is full denominator per-lane.
__global__ __launch_bounds__(256) void k_agg2(const int* __restrict__ rowptr,
                                              const int* __restrict__ csr,
                                              const float* __restrict__ ssrc,
                                              const float* __restrict__ sdst,
                                              const unsigned short* __restrict__ xs2,
                                              const float* __restrict__ bias,
                                              float* __restrict__ outp){
  int tid = blockIdx.x * 256 + threadIdx.x;
  int n = tid >> 3;
  int lm = threadIdx.x & 7;
  if (n >= NN) return;
  int start = rowptr[n], end = rowptr[n + 1];
  float sdn = sdst[n];
  const uint4* xp = (const uint4*)xs2 + lm;

  float sloc = 0.f;
  f32x2 acc[4];
  #pragma unroll
  for (int i = 0; i < 4; i++){ f32x2 z = {0.f, 0.f}; acc[i] = z; }

  int e = start;
  int sA = csr[e];
  float svA = ssrc[sA];
  uint4 uA = xp[(size_t)sA * 8];
  for (; e + 1 < end; e++){
    int sB = csr[e + 1];
    float svB = ssrc[sB];
    uint4 uB = xp[(size_t)sB * 8];
    float w = __expf(lrelu(svA + sdn));
    sloc += w;
    fma8p(acc, w, uA);
    svA = svB; uA = uB;
  }
  float w = __expf(lrelu(svA + sdn));
  sloc += w;
  fma8p(acc, w, uA);

  float inv = 1.f / sloc;

  float o[8];
  #pragma unroll
  for (int i = 0; i < 8; i++)
    o[i] = tanhf(lrelu(acc[i >> 1][i & 1] * inv + bias[lm * 8 + i]));
  float* op = outp + (size_t)n * 64 + lm * 8;
  *(float4*)op       = make_float4(o[0], o[1], o[2], o[3]);
  *(float4*)(op + 4) = make_float4(o[4], o[5], o[6], o[7]);
}

extern "C" void kernel_launch(void* const* d_in, const int* in_sizes, int n_in,
                              void* d_out, int out_size, void* d_ws, size_t ws_size,
                              hipStream_t stream){
  const float* type_emb  = (const float*)d_in[0];
  const int*   edge      = (const int*)d_in[1];
  const float* W         = (const float*)d_in[2];
  const float* att_src   = (const float*)d_in[3];
  const float* att_dst   = (const float*)d_in[4];
  const float* bias      = (const float*)d_in[5];
  const float* W_out     = (const float*)d_in[6];
  const float* att_src_o = (const float*)d_in[7];
  const float* att_dst_o = (const float*)d_in[8];
  const float* bias_o    = (const float*)d_in[9];
  float* out = (float*)d_out;
  (void)in_sizes; (void)n_in; (void)out_size; (void)ws_size;

  char* ws = (char*)d_ws;
  size_t off = 0;
  auto alloc = [&](size_t bytes) -> void* {
    void* p = ws + off;
    off = (off + bytes + 255) & ~(size_t)255;
    return p;
  };
  unsigned short* xs_all = (unsigned short*)alloc((size_t)NN * 512 * 2); // [N][4*128] bf16
  unsigned short* x1h    = (unsigned short*)alloc((size_t)NN * 512 * 2); // [N][512] bf16
  unsigned short* xs2    = (unsigned short*)alloc((size_t)NN * 64 * 2);  // [N][64] bf16
  float* ssrc1 = (float*)alloc((size_t)4 * SROWS * 4);  // head-major [4][SROWS]
  float* sdst1 = (float*)alloc((size_t)4 * SROWS * 4);
  float* ssrc2 = (float*)alloc((size_t)SROWS * 4);
  float* sdst2 = (float*)alloc((size_t)SROWS * 4);
  int* cnt    = (int*)alloc((size_t)NN * 4);
  int* rowptr = (int*)alloc((size_t)(NN + 1) * 4);
  int* fill   = (int*)alloc((size_t)NN * 4);
  int* csr    = (int*)alloc((size_t)ETOT * 4);
  int* p1     = (int*)alloc((size_t)NSCAN * 4 + 256);
  int* p2     = (int*)alloc((size_t)NSCAN * 4 + 256);
  unsigned short* Bh1 = (unsigned short*)alloc((size_t)4 * 128 * 128 * 2);
  unsigned short* Bl1 = (unsigned short*)alloc((size_t)4 * 128 * 128 * 2);
  unsigned short* Bh2 = (unsigned short*)alloc((size_t)512 * 64 * 2);
  unsigned short* Bl2 = (unsigned short*)alloc((size_t)512 * 64 * 2);

  // ---- CSR build (dst-sorted) ----
  hipMemsetAsync(cnt, 0, (size_t)NN * 4, stream);
  hipMemsetAsync(fill, 0, (size_t)NN * 4, stream);
  k_hist<<<(ETOT + 255) / 256, 256, 0, stream>>>(edge + EE, cnt);
  k_scan1<<<NSCAN, 256, 0, stream>>>(cnt, p1);
  k_scan2<<<1, 64, 0, stream>>>(p1, p2);
  k_scan3<<<NSCAN, 256, 0, stream>>>(cnt, p2, rowptr);
  k_scatter<<<(ETOT + 255) / 256, 256, 0, stream>>>(edge, edge + EE, rowptr, fill, csr);

  // ---- weight conversion ----
  k_convB<<<(4 * 128 * 128 + 255) / 256, 256, 0, stream>>>(W, Bh1, Bl1, 128, 128, 4 * 128 * 128);
  k_convB<<<(512 * 64 + 255) / 256, 256, 0, stream>>>(W_out, Bh2, Bl2, 512, 64, 512 * 64);

  // ---- layer 1: all 4 heads (GEMM + fused att row-dots) ----
  gemm_split<128, 512><<<dim3(391, 4), 256, 0, stream>>>(
      type_emb, Bh1, Bl1, xs_all, NN, 128, att_src, att_dst, ssrc1, sdst1);
  k_agg1<<<dim3(3125, 4), 256, 0, stream>>>(rowptr, csr, ssrc1, sdst1, xs_all, bias, x1h);

  // ---- layer 2 (bf16 A, split B) ----
  gemm_ps<64, 64><<<dim3(391, 1), 256, 0, stream>>>(
      x1h, Bh2, Bl2, xs2, NN, 512, att_src_o, att_dst_o, ssrc2, sdst2);
  k_agg2<<<1563, 256, 0, stream>>>(rowptr, csr, ssrc2, sdst2, xs2, bias_o, out);
}

// Round 15
// 432.270 us; speedup vs baseline: 1.0556x; 1.0079x over previous
//
#include <hip/hip_runtime.h>
#include <cmath>

#define NN 50000
#define EE 800000
#define ETOT (EE + NN)
#define NSCAN ((NN + 1023) / 1024)
#define SROWS 50048   // padded rows for head-major logit arrays

typedef __bf16 v8bf __attribute__((ext_vector_type(8)));
typedef float f32x4 __attribute__((ext_vector_type(4)));
typedef float f32x2 __attribute__((ext_vector_type(2)));

__device__ __forceinline__ float lrelu(float x){ return x > 0.0f ? x : 0.2f * x; }
__device__ __forceinline__ unsigned short f2bf_rne(float x){
  unsigned int u = __float_as_uint(x);
  u += 0x7fffu + ((u >> 16) & 1u);
  return (unsigned short)(u >> 16);
}
__device__ __forceinline__ float bf2f(unsigned short b){
  return __uint_as_float(((unsigned int)b) << 16);
}
// async global->LDS, 16B per lane. LDS dest = uniform base + lane*16;
// global src is per-lane.
__device__ __forceinline__ void async_ld16(const void* g, void* l){
  __builtin_amdgcn_global_load_lds(
      (const __attribute__((address_space(1))) unsigned int*)g,
      (__attribute__((address_space(3))) unsigned int*)l, 16, 0, 0);
}
// packed accumulate: acc[4] of float2 -> v_pk_fma_f32
__device__ __forceinline__ void fma8p(f32x2* acc, float w, uint4 u){
  f32x2 w2 = {w, w};
  f32x2 a0, a1, a2, a3;
  a0[0] = __uint_as_float(u.x << 16); a0[1] = __uint_as_float(u.x & 0xffff0000u);
  a1[0] = __uint_as_float(u.y << 16); a1[1] = __uint_as_float(u.y & 0xffff0000u);
  a2[0] = __uint_as_float(u.z << 16); a2[1] = __uint_as_float(u.z & 0xffff0000u);
  a3[0] = __uint_as_float(u.w << 16); a3[1] = __uint_as_float(u.w & 0xffff0000u);
  acc[0] += w2 * a0;
  acc[1] += w2 * a1;
  acc[2] += w2 * a2;
  acc[3] += w2 * a3;
}

// ---------------- CSR build ----------------
__global__ void k_hist(const int* __restrict__ dst, int* __restrict__ cnt){
  int i = blockIdx.x * 256 + threadIdx.x;
  if (i >= ETOT) return;
  int d = (i < EE) ? dst[i] : (i - EE);
  atomicAdd(&cnt[d], 1);
}

__global__ void k_scan1(const int* __restrict__ cnt, int* __restrict__ part){
  __shared__ int sm[256];
  int b = blockIdx.x, t = threadIdx.x;
  int base = b * 1024 + t * 4;
  int s = 0;
  #pragma unroll
  for (int j = 0; j < 4; j++) if (base + j < NN) s += cnt[base + j];
  sm[t] = s; __syncthreads();
  for (int off = 128; off; off >>= 1){
    if (t < off) sm[t] += sm[t + off];
    __syncthreads();
  }
  if (t == 0) part[b] = sm[0];
}

__global__ void k_scan2(const int* __restrict__ part, int* __restrict__ part2){
  if (threadIdx.x == 0 && blockIdx.x == 0){
    int run = 0;
    for (int i = 0; i < NSCAN; i++){ part2[i] = run; run += part[i]; }
  }
}

__global__ void k_scan3(const int* __restrict__ cnt, const int* __restrict__ part2,
                        int* __restrict__ rowptr){
  __shared__ int sm[256];
  int b = blockIdx.x, t = threadIdx.x;
  int base = b * 1024 + t * 4;
  int v[4]; int s = 0;
  #pragma unroll
  for (int j = 0; j < 4; j++){ v[j] = (base + j < NN) ? cnt[base + j] : 0; s += v[j]; }
  sm[t] = s; __syncthreads();
  for (int off = 1; off < 256; off <<= 1){
    int x = (t >= off) ? sm[t - off] : 0;
    __syncthreads();
    sm[t] += x;
    __syncthreads();
  }
  int run = part2[b] + sm[t] - s;
  #pragma unroll
  for (int j = 0; j < 4; j++){
    if (base + j < NN){ rowptr[base + j] = run; run += v[j]; }
  }
  if (b == 0 && t == 0) rowptr[NN] = ETOT;
}

__global__ void k_scatter(const int* __restrict__ src, const int* __restrict__ dst,
                          const int* __restrict__ rowptr, int* __restrict__ fill,
                          int* __restrict__ csr){
  int i = blockIdx.x * 256 + threadIdx.x;
  if (i >= ETOT) return;
  int s, d;
  if (i < EE){ s = src[i]; d = dst[i]; } else { s = d = i - EE; }
  int pos = rowptr[d] + atomicAdd(&fill[d], 1);
  csr[pos] = s;
}

// ---------------- weight conversion: fp32 [.,K,N] -> bf16 hi/lo [.,K/8,N,8] ----
__global__ void k_convB(const float* __restrict__ B, unsigned short* __restrict__ bh,
                        unsigned short* __restrict__ bl, int K, int N, int total){
  int i = blockIdx.x * 256 + threadIdx.x;
  if (i >= total) return;
  int per = K * N;
  int h = i / per, rem = i - h * per;
  int k = rem / N, n = rem - k * N;
  float x = B[i];
  unsigned short hb = f2bf_rne(x);
  unsigned short lb = f2bf_rne(x - bf2f(hb));
  size_t o = (size_t)h * per + ((size_t)(k >> 3) * N + n) * 8 + (k & 7);
  bh[o] = hb; bl[o] = lb;
}

// ---------------- layer-1 GEMM: A single bf16 (staged from fp32), B split ----
// B staged via async global_load_lds (16B/lane); A converts in-flight (VGPR).
template<int BN, int OSTR>
__global__ __launch_bounds__(256) void gemm_split(const float* __restrict__ A,
                                                  const unsigned short* __restrict__ Bh,
                                                  const unsigned short* __restrict__ Bl,
                                                  unsigned short* __restrict__ out,
                                                  int M, int K,
                                                  const float* __restrict__ att_s,
                                                  const float* __restrict__ att_d,
                                                  float* __restrict__ ssrc,
                                                  float* __restrict__ sdst){
  const int t = threadIdx.x;
  const int wv = t >> 6, lane = t & 63;
  const int m0 = blockIdx.x * 128;
  const int h = blockIdx.y;
  A  += (size_t)h * M * K;
  Bh += (size_t)h * (K >> 3) * BN * 8;
  Bl += (size_t)h * (K >> 3) * BN * 8;
  const int colOff = h * BN;

  __shared__ v8bf sA[4][128];
  __shared__ v8bf sBh[4][BN];
  __shared__ v8bf sBl[4][BN];

  f32x4 acc[2][BN / 16];
  #pragma unroll
  for (int i = 0; i < 2; i++)
    #pragma unroll
    for (int j = 0; j < BN / 16; j++){
      f32x4 z = {0.f, 0.f, 0.f, 0.f};
      acc[i][j] = z;
    }

  const int mRow = t & 127;
  const int kh = (t >> 7) * 16;
  const bool valid = (m0 + mRow) < M;
  const int q = lane >> 4, lm = lane & 15;

  for (int k0 = 0; k0 < K; k0 += 32){
    // ---- stage B: async global->LDS, one 1KB wave-chunk per issue ----
    {
      const uint4* gh = (const uint4*)((const v8bf*)Bh + (size_t)(k0 >> 3) * BN);
      const uint4* gl = (const uint4*)((const v8bf*)Bl + (size_t)(k0 >> 3) * BN);
      uint4* dh = (uint4*)&sBh[0][0];
      uint4* dl = (uint4*)&sBl[0][0];
      constexpr int NCH = (4 * BN) / 64;
      #pragma unroll
      for (int c = wv; c < NCH; c += 4){
        async_ld16(gh + c * 64 + lane, dh + c * 64);
        async_ld16(gl + c * 64 + lane, dl + c * 64);
      }
    }
    // ---- stage A (fp32 -> bf16 in VGPRs) ----
    const float* ap = A + (size_t)(m0 + mRow) * K + k0 + kh;
    float4 v0, v1, v2, v3;
    if (valid){
      v0 = *(const float4*)(ap);
      v1 = *(const float4*)(ap + 4);
      v2 = *(const float4*)(ap + 8);
      v3 = *(const float4*)(ap + 12);
    } else {
      v0 = v1 = v2 = v3 = make_float4(0.f, 0.f, 0.f, 0.f);
    }
    #pragma unroll
    for (int g = 0; g < 2; g++){
      float xv[8];
      if (g == 0){ xv[0]=v0.x; xv[1]=v0.y; xv[2]=v0.z; xv[3]=v0.w; xv[4]=v1.x; xv[5]=v1.y; xv[6]=v1.z; xv[7]=v1.w; }
      else       { xv[0]=v2.x; xv[1]=v2.y; xv[2]=v2.z; xv[3]=v2.w; xv[4]=v3.x; xv[5]=v3.y; xv[6]=v3.z; xv[7]=v3.w; }
      v8bf H;
      #pragma unroll
      for (int i = 0; i < 8; i++) H[i] = (__bf16)xv[i];   // v_cvt_pk_bf16_f32, RNE
      sA[(kh >> 3) + g][mRow] = H;
    }
    __syncthreads();
    v8bf ah[2];
    #pragma unroll
    for (int rt = 0; rt < 2; rt++)
      ah[rt] = sA[q][wv * 32 + rt * 16 + lm];
    #pragma unroll
    for (int ct = 0; ct < BN / 16; ct++){
      v8bf bh = sBh[q][ct * 16 + lm];
      v8bf bl = sBl[q][ct * 16 + lm];
      #pragma unroll
      for (int rt = 0; rt < 2; rt++){
        acc[rt][ct] = __builtin_amdgcn_mfma_f32_16x16x32_bf16(ah[rt], bh, acc[rt][ct], 0, 0, 0);
        acc[rt][ct] = __builtin_amdgcn_mfma_f32_16x16x32_bf16(ah[rt], bl, acc[rt][ct], 0, 0, 0);
      }
    }
    __syncthreads();
  }

  float asv[BN / 16], adv[BN / 16];
  #pragma unroll
  for (int ct = 0; ct < BN / 16; ct++){
    asv[ct] = att_s[h * BN + ct * 16 + lm];
    adv[ct] = att_d[h * BN + ct * 16 + lm];
  }

  #pragma unroll
  for (int rt = 0; rt < 2; rt++){
    #pragma unroll
    for (int reg = 0; reg < 4; reg++){
      int r = m0 + wv * 32 + rt * 16 + q * 4 + reg;
      float d0 = 0.f, d1 = 0.f;
      #pragma unroll
      for (int ct = 0; ct < BN / 16; ct++){
        float v = acc[rt][ct][reg];
        d0 += v * asv[ct];
        d1 += v * adv[ct];
      }
      #pragma unroll
      for (int off = 1; off < 16; off <<= 1){
        d0 += __shfl_xor(d0, off, 64);
        d1 += __shfl_xor(d1, off, 64);
      }
      if (r < M){
        unsigned short* orow = out + (size_t)r * OSTR + colOff + lm;
        #pragma unroll
        for (int ct = 0; ct < BN / 16; ct++)
          orow[ct * 16] = f2bf_rne(acc[rt][ct][reg]);
        if (lm == 0){
          ssrc[(size_t)h * SROWS + r] = d0;
          sdst[(size_t)h * SROWS + r] = d1;
        }
      }
    }
  }
}

// ---------------- layer-2 GEMM (A single bf16, B split hi/lo) ---------------
// A and B staged via async global_load_lds.
template<int BN, int OSTR>
__global__ __launch_bounds__(256) void gemm_ps(const unsigned short* __restrict__ Ah,
                                               const unsigned short* __restrict__ Bh,
                                               const unsigned short* __restrict__ Bl,
                                               unsigned short* __restrict__ out,
                                               int M, int K,
                                               const float* __restrict__ att_s,
                                               const float* __restrict__ att_d,
                                               float* __restrict__ ssrc,
                                               float* __restrict__ sdst){
  const int t = threadIdx.x;
  const int wv = t >> 6, lane = t & 63;
  const int m0 = blockIdx.x * 128;
  const int h = blockIdx.y;
  const int colOff = h * BN;

  __shared__ v8bf sAh[4][128];
  __shared__ v8bf sBh[4][BN];
  __shared__ v8bf sBl[4][BN];

  f32x4 acc[2][BN / 16];
  #pragma unroll
  for (int i = 0; i < 2; i++)
    #pragma unroll
    for (int j = 0; j < BN / 16; j++){
      f32x4 z = {0.f, 0.f, 0.f, 0.f};
      acc[i][j] = z;
    }

  const int mRow = t & 127;
  const int kh = (t >> 7) * 16;
  const int k8 = kh >> 3;
  const int q = lane >> 4, lm = lane & 15;

  for (int k0 = 0; k0 < K; k0 += 32){
    // ---- stage A: async, wave-uniform LDS base + per-lane row-strided src ----
    {
      const unsigned short* aph = Ah + (size_t)(m0 + mRow) * K + k0 + kh;
      uint4* base0 = (uint4*)&sAh[k8][(wv & 1) * 64];
      uint4* base1 = (uint4*)&sAh[k8 + 1][(wv & 1) * 64];
      async_ld16(aph, base0);
      async_ld16(aph + 8, base1);
    }
    // ---- stage B: async ----
    {
      const uint4* gh = (const uint4*)((const v8bf*)Bh + (size_t)(k0 >> 3) * BN);
      const uint4* gl = (const uint4*)((const v8bf*)Bl + (size_t)(k0 >> 3) * BN);
      uint4* dh = (uint4*)&sBh[0][0];
      uint4* dl = (uint4*)&sBl[0][0];
      constexpr int NCH = (4 * BN) / 64;
      #pragma unroll
      for (int c = wv; c < NCH; c += 4){
        async_ld16(gh + c * 64 + lane, dh + c * 64);
        async_ld16(gl + c * 64 + lane, dl + c * 64);
      }
    }
    __syncthreads();
    v8bf ah[2];
    #pragma unroll
    for (int rt = 0; rt < 2; rt++){
      int m = wv * 32 + rt * 16 + lm;
      ah[rt] = sAh[q][m];
    }
    #pragma unroll
    for (int ct = 0; ct < BN / 16; ct++){
      v8bf bh = sBh[q][ct * 16 + lm];
      v8bf bl = sBl[q][ct * 16 + lm];
      #pragma unroll
      for (int rt = 0; rt < 2; rt++){
        acc[rt][ct] = __builtin_amdgcn_mfma_f32_16x16x32_bf16(ah[rt], bh, acc[rt][ct], 0, 0, 0);
        acc[rt][ct] = __builtin_amdgcn_mfma_f32_16x16x32_bf16(ah[rt], bl, acc[rt][ct], 0, 0, 0);
      }
    }
    __syncthreads();
  }

  float asv[BN / 16], adv[BN / 16];
  #pragma unroll
  for (int ct = 0; ct < BN / 16; ct++){
    asv[ct] = att_s[h * BN + ct * 16 + lm];
    adv[ct] = att_d[h * BN + ct * 16 + lm];
  }

  #pragma unroll
  for (int rt = 0; rt < 2; rt++){
    #pragma unroll
    for (int reg = 0; reg < 4; reg++){
      int r = m0 + wv * 32 + rt * 16 + q * 4 + reg;
      float d0 = 0.f, d1 = 0.f;
      #pragma unroll
      for (int ct = 0; ct < BN / 16; ct++){
        float v = acc[rt][ct][reg];
        d0 += v * asv[ct];
        d1 += v * adv[ct];
      }
      #pragma unroll
      for (int off = 1; off < 16; off <<= 1){
        d0 += __shfl_xor(d0, off, 64);
        d1 += __shfl_xor(d1, off, 64);
      }
      if (r < M){
        unsigned short* orow = out + (size_t)r * OSTR + colOff + lm;
        #pragma unroll
        for (int ct = 0; ct < BN / 16; ct++)
          orow[ct * 16] = f2bf_rne(acc[rt][ct][reg]);
        if (lm == 0){
          ssrc[(size_t)h * SROWS + r] = d0;
          sdst[(size_t)h * SROWS + r] = d1;
        }
      }
    }
  }
}

// ---------------- layer-1 aggregation: 16-lane group per (node, head) --------
// Round-4/9 structure + INDEX-PREFETCH depth-3: csr[e+2] is loaded each
// iteration so the dependent ssrc/xs gathers for e+1 issue immediately from
// the prior iteration's index (csr->gather chain spans a full compute body).
// Row data stays depth-2. x1 written as single bf16 (hi only).
__global__ __launch_bounds__(256) void k_agg1(const int* __restrict__ rowptr,
                                              const int* __restrict__ csr,
                                              const float* __restrict__ ssrc,
                                              const float* __restrict__ sdst,
                                              const unsigned short* __restrict__ xs_all,
                                              const float* __restrict__ bias,
                                              unsigned short* __restrict__ x1h){
  int tid = blockIdx.x * 256 + threadIdx.x;
  int n = tid >> 4;
  int lm = threadIdx.x & 15;
  int h = blockIdx.y;
  if (n >= NN) return;
  int start = rowptr[n], end = rowptr[n + 1];
  const float* sp = ssrc + (size_t)h * SROWS;
  float sdn = sdst[(size_t)h * SROWS + n];
  const uint4* xp = (const uint4*)xs_all + h * 16 + lm;

  float sloc = 0.f;
  f32x2 acc[4];
  #pragma unroll
  for (int i = 0; i < 4; i++){ f32x2 z = {0.f, 0.f}; acc[i] = z; }

  int e = start;
  int s0 = csr[e];
  float sv = sp[s0];
  uint4 u = xp[(size_t)s0 * 64];
  int sN = (e + 1 < end) ? csr[e + 1] : 0;
  for (; e + 2 < end; e++){
    int sNN = csr[e + 2];           // index prefetch (2 ahead)
    float svB = sp[sN];             // row loads for e+1 (index from last iter)
    uint4 uB = xp[(size_t)sN * 64];
    float w = __expf(lrelu(sv + sdn));
    sloc += w;
    fma8p(acc, w, u);
    sv = svB; u = uB; sN = sNN;
  }
  float w = __expf(lrelu(sv + sdn));
  sloc += w;
  fma8p(acc, w, u);
  if (e + 1 < end){
    float svB = sp[sN];
    uint4 uB = xp[(size_t)sN * 64];
    w = __expf(lrelu(svB + sdn));
    sloc += w;
    fma8p(acc, w, uB);
  }

  float inv = 1.f / sloc;

  const float* bp = bias + h * 128 + lm * 8;
  float4 b0 = *(const float4*)bp, b1 = *(const float4*)(bp + 4);
  float bb[8] = {b0.x, b0.y, b0.z, b0.w, b1.x, b1.y, b1.z, b1.w};
  union { uint4 q; unsigned short u[8]; } HH;
  #pragma unroll
  for (int i = 0; i < 8; i++){
    float o = lrelu(acc[i >> 1][i & 1] * inv + bb[i]);
    HH.u[i] = f2bf_rne(o);
  }
  size_t ofs = (size_t)n * 512 + h * 128 + lm * 8;
  *(uint4*)(x1h + ofs) = HH.q;
}

// ---------------- layer-2 aggregation: 8-lane group per node ------------------
// Same index-prefetch depth-3 structure.
__global__ __launch_bounds__(256) void k_agg2(const int* __restrict__ rowptr,
                                              const int* __restrict__ csr,
                                              const float* __restrict__ ssrc,
                                              const float* __restrict__ sdst,
                                              const unsigned short* __restrict__ xs2,
                                              const float* __restrict__ bias,
                                              float* __restrict__ outp){
  int tid = blockIdx.x * 256 + threadIdx.x;
  int n = tid >> 3;
  int lm = threadIdx.x & 7;
  if (n >= NN) return;
  int start = rowptr[n], end = rowptr[n + 1];
  float sdn = sdst[n];
  const uint4* xp = (const uint4*)xs2 + lm;

  float sloc = 0.f;
  f32x2 acc[4];
  #pragma unroll
  for (int i = 0; i < 4; i++){ f32x2 z = {0.f, 0.f}; acc[i] = z; }

  int e = start;
  int s0 = csr[e];
  float sv = ssrc[s0];
  uint4 u = xp[(size_t)s0 * 8];
  int sN = (e + 1 < end) ? csr[e + 1] : 0;
  for (; e + 2 < end; e++){
    int sNN = csr[e + 2];
    float svB = ssrc[sN];
    uint4 uB = xp[(size_t)sN * 8];
    float w = __expf(lrelu(sv + sdn));
    sloc += w;
    fma8p(acc, w, u);
    sv = svB; u = uB; sN = sNN;
  }
  float w = __expf(lrelu(sv + sdn));
  sloc += w;
  fma8p(acc, w, u);
  if (e + 1 < end){
    float svB = ssrc[sN];
    uint4 uB = xp[(size_t)sN * 8];
    w = __expf(lrelu(svB + sdn));
    sloc += w;
    fma8p(acc, w, uB);
  }

  float inv = 1.f / sloc;

  float o[8];
  #pragma unroll
  for (int i = 0; i < 8; i++)
    o[i] = tanhf(lrelu(acc[i >> 1][i & 1] * inv + bias[lm * 8 + i]));
  float* op = outp + (size_t)n * 64 + lm * 8;
  *(float4*)op       = make_float4(o[0], o[1], o[2], o[3]);
  *(float4*)(op + 4) = make_float4(o[4], o[5], o[6], o[7]);
}

extern "C" void kernel_launch(void* const* d_in, const int* in_sizes, int n_in,
                              void* d_out, int out_size, void* d_ws, size_t ws_size,
                              hipStream_t stream){
  const float* type_emb  = (const float*)d_in[0];
  const int*   edge      = (const int*)d_in[1];
  const float* W         = (const float*)d_in[2];
  const float* att_src   = (const float*)d_in[3];
  const float* att_dst   = (const float*)d_in[4];
  const float* bias      = (const float*)d_in[5];
  const float* W_out     = (const float*)d_in[6];
  const float* att_src_o = (const float*)d_in[7];
  const float* att_dst_o = (const float*)d_in[8];
  const float* bias_o    = (const float*)d_in[9];
  float* out = (float*)d_out;
  (void)in_sizes; (void)n_in; (void)out_size; (void)ws_size;

  char* ws = (char*)d_ws;
  size_t off = 0;
  auto alloc = [&](size_t bytes) -> void* {
    void* p = ws + off;
    off = (off + bytes + 255) & ~(size_t)255;
    return p;
  };
  unsigned short* xs_all = (unsigned short*)alloc((size_t)NN * 512 * 2); // [N][4*128] bf16
  unsigned short* x1h    = (unsigned short*)alloc((size_t)NN * 512 * 2); // [N][512] bf16
  unsigned short* xs2    = (unsigned short*)alloc((size_t)NN * 64 * 2);  // [N][64] bf16
  float* ssrc1 = (float*)alloc((size_t)4 * SROWS * 4);  // head-major [4][SROWS]
  float* sdst1 = (float*)alloc((size_t)4 * SROWS * 4);
  float* ssrc2 = (float*)alloc((size_t)SROWS * 4);
  float* sdst2 = (float*)alloc((size_t)SROWS * 4);
  int* cnt    = (int*)alloc((size_t)NN * 4);
  int* rowptr = (int*)alloc((size_t)(NN + 1) * 4);
  int* fill   = (int*)alloc((size_t)NN * 4);
  int* csr    = (int*)alloc((size_t)ETOT * 4);
  int* p1     = (int*)alloc((size_t)NSCAN * 4 + 256);
  int* p2     = (int*)alloc((size_t)NSCAN * 4 + 256);
  unsigned short* Bh1 = (unsigned short*)alloc((size_t)4 * 128 * 128 * 2);
  unsigned short* Bl1 = (unsigned short*)alloc((size_t)4 * 128 * 128 * 2);
  unsigned short* Bh2 = (unsigned short*)alloc((size_t)512 * 64 * 2);
  unsigned short* Bl2 = (unsigned short*)alloc((size_t)512 * 64 * 2);

  // ---- CSR build (dst-sorted) ----
  hipMemsetAsync(cnt, 0, (size_t)NN * 4, stream);
  hipMemsetAsync(fill, 0, (size_t)NN * 4, stream);
  k_hist<<<(ETOT + 255) / 256, 256, 0, stream>>>(edge + EE, cnt);
  k_scan1<<<NSCAN, 256, 0, stream>>>(cnt, p1);
  k_scan2<<<1, 64, 0, stream>>>(p1, p2);
  k_scan3<<<NSCAN, 256, 0, stream>>>(cnt, p2, rowptr);
  k_scatter<<<(ETOT + 255) / 256, 256, 0, stream>>>(edge, edge + EE, rowptr, fill, csr);

  // ---- weight conversion ----
  k_convB<<<(4 * 128 * 128 + 255) / 256, 256, 0, stream>>>(W, Bh1, Bl1, 128, 128, 4 * 128 * 128);
  k_convB<<<(512 * 64 + 255) / 256, 256, 0, stream>>>(W_out, Bh2, Bl2, 512, 64, 512 * 64);

  // ---- layer 1: all 4 heads (GEMM + fused att row-dots) ----
  gemm_split<128, 512><<<dim3(391, 4), 256, 0, stream>>>(
      type_emb, Bh1, Bl1, xs_all, NN, 128, att_src, att_dst, ssrc1, sdst1);
  k_agg1<<<dim3(3125, 4), 256, 0, stream>>>(rowptr, csr, ssrc1, sdst1, xs_all, bias, x1h);

  // ---- layer 2 (bf16 A, split B) ----
  gemm_ps<64, 64><<<dim3(391, 1), 256, 0, stream>>>(
      x1h, Bh2, Bl2, xs2, NN, 512, att_src_o, att_dst_o, ssrc2, sdst2);
  k_agg2<<<1563, 256, 0, stream>>>(rowptr, csr, ssrc2, sdst2, xs2, bias_o, out);
}